// Round 6
// baseline (946.818 us; speedup 1.0000x reference)
//
#include <hip/hip_runtime.h>

// Conv2dInt8 R9 (= R8 resubmit; round-5 bench died on container acquire again, no kernel
// verdict — identical failure mode as round 3, which passed unchanged on resubmit).
// Raise resident blocks/CU 4 -> 7 to fix HBM phase-serialization.
// R7 post-mortem: traffic ideal (269+262 MB) but HBM duty cycle 44% (2.94 TB/s).
// All compute resources are individually small (MFMA ~13us, VALU ~15us, LDS ~15us);
// the 185us comes from staging/compute phases of the 4 lockstep resident blocks
// serializing: HBM idles during every compute phase. Fix: move the 12.3KB weight
// pack out of LDS into d_ws (one-time 12-block kernel, proven R3 pattern); conv
// reads A-frags straight from global (coalesced 1KB/wave, L2-resident).
// LDS 34.3 -> 21.8 KB => 7 blocks/CU (28 waves), __launch_bounds__(256,7).
// Staging + MFMA + epilogue byte-identical to R7 (passed, absmax 0.25).

#define N_IMG 8
#define CIN   32
#define COUT  32
#define HD    512
#define WD    512
#define TH    8
#define TW    64
#define XROWS 10
#define XCOLS 68
#define PLANE (XROWS * XCOLS * 16)   // 10880 B per 16-channel plane
#define WP_BYTES (6 * 32 * 64)       // 12288

typedef int intx4 __attribute__((ext_vector_type(4)));
typedef float floatx4 __attribute__((ext_vector_type(4)));

// ---------------- dispatch 1: pack weights int32 OIHW -> int8 wp in d_ws ----------------
// wp[(kh*2+pair)*32+cout][sel*32+cin], kw = pair*2+sel; kw==3 slots zero. (R5/R7 formula.)
__global__ __launch_bounds__(256) void wpack_kernel(const int* __restrict__ wq,
                                                    unsigned int* __restrict__ wp) {
    const int d    = blockIdx.x * 256 + threadIdx.x;   // dword id, 3072 total
    const int row  = d >> 4;
    const int k0   = (d & 15) * 4;
    const int khp  = row >> 5;
    const int cout = row & 31;
    const int kh   = khp >> 1;
    const int pr   = khp & 1;
    const int sel  = k0 >> 5;
    const int kw   = pr * 2 + sel;
    unsigned int pk = 0u;
    if (kw < 3) {
        const int cin0 = k0 & 31;
        const int* wqp = wq + ((cout * CIN + cin0) * 3 + kh) * 3 + kw;  // OIHW, cin stride 9
        unsigned int b0 = (unsigned int)(wqp[0]  - 128) & 0xffu;
        unsigned int b1 = (unsigned int)(wqp[9]  - 128) & 0xffu;
        unsigned int b2 = (unsigned int)(wqp[18] - 128) & 0xffu;
        unsigned int b3 = (unsigned int)(wqp[27] - 128) & 0xffu;
        pk = b0 | (b1 << 8) | (b2 << 16) | (b3 << 24);
    }
    wp[d] = pk;
}

// ---------------- dispatch 2: fused quant + conv, 7 blocks/CU ----------------
__global__ __launch_bounds__(256, 7) void conv8_hi(const float* __restrict__ x,
                                                   const char* __restrict__ wp,
                                                   const int* __restrict__ bias,
                                                   float* __restrict__ out)
{
    __shared__ alignas(16) unsigned char xs[2 * PLANE];   // 21760 B (only LDS)

    const int tid = threadIdx.x;
    const int bx = blockIdx.x;   // w tile (64 px)
    const int by = blockIdx.y;   // h tile (8 rows)
    const int n  = blockIdx.z;

    // ---- stage input: fp32 NCHW -> int8 [half][pix][16] LDS planes (R7 verbatim) ----
    const int h0 = by * TH - 1;
    for (int t = tid; t < 360; t += 256) {
        if (t < 320) {
            const int g    = t & 15;
            const int half = (t >> 4) & 1;
            const int row  = t >> 5;
            const int h    = h0 + row;
            const bool inb = (unsigned)h < (unsigned)HD;
            floatx4 v[16];
            if (inb) {
                const float* xp = x + ((size_t)(n * CIN + half * 16) * HD + h) * WD + bx * TW + g * 4;
#pragma unroll
                for (int c = 0; c < 16; ++c)
                    v[c] = *(const floatx4*)(xp + (size_t)c * (HD * WD));
            }
            __builtin_amdgcn_sched_barrier(0);   // keep the load batch issued together
            unsigned char* dst = xs + half * PLANE + ((size_t)row * XCOLS + 1 + g * 4) * 16;
#pragma unroll
            for (int j = 0; j < 4; ++j) {        // pixel within the float4
                unsigned int pk[4] = {0u, 0u, 0u, 0u};
                if (inb) {
#pragma unroll
                    for (int c4 = 0; c4 < 4; ++c4) {
                        unsigned int bb = 0u;
#pragma unroll
                        for (int cc = 0; cc < 4; ++cc) {
                            float q = rintf(v[c4 * 4 + cc][j] / 0.05f);   // identical numerics
                            q = fminf(fmaxf(q, -128.0f), 127.0f);
                            bb |= ((unsigned int)(int)q & 0xffu) << (cc * 8);
                        }
                        pk[c4] = bb;
                    }
                }
                *(uint4*)(dst + j * 16) = make_uint4(pk[0], pk[1], pk[2], pk[3]);
            }
        } else {
            const int u    = t - 320;            // 0..39: halo cols pc in {0,65}
            const int pc   = (u & 1) ? 65 : 0;
            const int half = (u >> 1) & 1;
            const int row  = u >> 2;
            const int h    = h0 + row;
            const int w    = bx * TW - 1 + pc;
            const bool inb = (unsigned)h < (unsigned)HD && (unsigned)w < (unsigned)WD;
            float v[16];
            if (inb) {
                const float* xp = x + ((size_t)(n * CIN + half * 16) * HD + h) * WD + w;
#pragma unroll
                for (int c = 0; c < 16; ++c)
                    v[c] = xp[(size_t)c * (HD * WD)];
            }
            __builtin_amdgcn_sched_barrier(0);
            unsigned int pk[4] = {0u, 0u, 0u, 0u};
            if (inb) {
#pragma unroll
                for (int c4 = 0; c4 < 4; ++c4) {
                    unsigned int bb = 0u;
#pragma unroll
                    for (int cc = 0; cc < 4; ++cc) {
                        float q = rintf(v[c4 * 4 + cc] / 0.05f);
                        q = fminf(fmaxf(q, -128.0f), 127.0f);
                        bb |= ((unsigned int)(int)q & 0xffu) << (cc * 8);
                    }
                    pk[c4] = bb;
                }
            }
            *(uint4*)(xs + half * PLANE + ((size_t)row * XCOLS + pc) * 16) =
                make_uint4(pk[0], pk[1], pk[2], pk[3]);
        }
    }

    __syncthreads();

    // ---- compute: R7 MFMA plan; A-frags read from GLOBAL wp (L2-resident) ----
    const int lane = tid & 63;
    const int wave = tid >> 6;
    const int l15  = lane & 15;
    const int quad = lane >> 4;

    intx4 Af[3][2][2];
#pragma unroll
    for (int kh = 0; kh < 3; ++kh)
#pragma unroll
        for (int p = 0; p < 2; ++p)
#pragma unroll
            for (int hf = 0; hf < 2; ++hf)
                Af[kh][p][hf] = *(const intx4*)(wp + (((kh * 2 + p) * 32 + hf * 16 + l15) << 6) + quad * 16);

    int bi0[4], bi1[4];
#pragma unroll
    for (int r = 0; r < 4; ++r) { bi0[r] = bias[quad * 4 + r]; bi1[r] = bias[16 + quad * 4 + r]; }

    const int wseg = wave * 16;
    // k = quad*16 + j -> kw-sel = quad>>1 (pixel offset), ch-half = quad&1 (plane), cin = (quad&1)*16 + j
    const unsigned char* bbase = xs + (size_t)(quad & 1) * PLANE
                               + ((size_t)(wseg + l15 + (quad >> 1))) * 16;

#pragma unroll
    for (int it = 0; it < 4; ++it) {
        intx4 Bw[4][2];
#pragma unroll
        for (int r = 0; r < 4; ++r)
#pragma unroll
            for (int p = 0; p < 2; ++p)
                Bw[r][p] = *(const intx4*)(bbase + (size_t)((2 * it + r) * XCOLS + 2 * p) * 16);

        intx4 acc[2][2];
#pragma unroll
        for (int o = 0; o < 2; ++o)
#pragma unroll
            for (int hf = 0; hf < 2; ++hf)
                acc[o][hf] = (intx4){0, 0, 0, 0};

#pragma unroll
        for (int o = 0; o < 2; ++o)
#pragma unroll
            for (int kh = 0; kh < 3; ++kh)
#pragma unroll
                for (int p = 0; p < 2; ++p) {
                    const intx4 b = Bw[o + kh][p];
                    acc[o][0] = __builtin_amdgcn_mfma_i32_16x16x64_i8(Af[kh][p][0], b, acc[o][0], 0, 0, 0);
                    acc[o][1] = __builtin_amdgcn_mfma_i32_16x16x64_i8(Af[kh][p][1], b, acc[o][1], 0, 0, 0);
                }

#pragma unroll
        for (int o = 0; o < 2; ++o) {
            const int h = by * TH + 2 * it + o;
            float* op0 = out + (((size_t)n * COUT + quad * 4) * HD + h) * WD + bx * TW + wseg + l15;
            float* op1 = op0 + (size_t)16 * HD * WD;
#pragma unroll
            for (int r = 0; r < 4; ++r) {
                int v0 = acc[o][0][r] + bi0[r];
                float yq0 = rintf((float)v0 * 0.01f);
                yq0 = fminf(fmaxf(yq0, -127.f), 127.f);
                op0[(size_t)r * (HD * WD)] = fmaxf(yq0 * 0.1f, 0.f);
                int v1 = acc[o][1][r] + bi1[r];
                float yq1 = rintf((float)v1 * 0.01f);
                yq1 = fminf(fmaxf(yq1, -127.f), 127.f);
                op1[(size_t)r * (HD * WD)] = fmaxf(yq1 * 0.1f, 0.f);
            }
        }
    }
}

// ---------------- fallback: R7 self-contained kernel (weights staged in LDS) ----------------
__global__ __launch_bounds__(256, 4) void conv8_fused_lds(const float* __restrict__ x,
                                                          const int* __restrict__ wq,
                                                          const int* __restrict__ bias,
                                                          float* __restrict__ out)
{
    __shared__ alignas(16) unsigned char xs[2 * PLANE];
    __shared__ alignas(16) char wp[6 * 32 * 64];

    const int tid = threadIdx.x;
    const int bx = blockIdx.x, by = blockIdx.y, n = blockIdx.z;

#pragma unroll
    for (int k = 0; k < 12; ++k) {
        const int d    = tid + k * 256;
        const int row  = d >> 4;
        const int k0   = (d & 15) * 4;
        const int khp  = row >> 5;
        const int cout = row & 31;
        const int kh   = khp >> 1;
        const int pr   = khp & 1;
        const int sel  = k0 >> 5;
        const int kw   = pr * 2 + sel;
        unsigned int pk = 0u;
        if (kw < 3) {
            const int cin0 = k0 & 31;
            const int* wqp = wq + ((cout * CIN + cin0) * 3 + kh) * 3 + kw;
            unsigned int b0 = (unsigned int)(wqp[0]  - 128) & 0xffu;
            unsigned int b1 = (unsigned int)(wqp[9]  - 128) & 0xffu;
            unsigned int b2 = (unsigned int)(wqp[18] - 128) & 0xffu;
            unsigned int b3 = (unsigned int)(wqp[27] - 128) & 0xffu;
            pk = b0 | (b1 << 8) | (b2 << 16) | (b3 << 24);
        }
        *(unsigned int*)(wp + d * 4) = pk;
    }

    const int h0 = by * TH - 1;
    for (int t = tid; t < 360; t += 256) {
        if (t < 320) {
            const int g    = t & 15;
            const int half = (t >> 4) & 1;
            const int row  = t >> 5;
            const int h    = h0 + row;
            const bool inb = (unsigned)h < (unsigned)HD;
            floatx4 v[16];
            if (inb) {
                const float* xp = x + ((size_t)(n * CIN + half * 16) * HD + h) * WD + bx * TW + g * 4;
#pragma unroll
                for (int c = 0; c < 16; ++c)
                    v[c] = *(const floatx4*)(xp + (size_t)c * (HD * WD));
            }
            __builtin_amdgcn_sched_barrier(0);
            unsigned char* dst = xs + half * PLANE + ((size_t)row * XCOLS + 1 + g * 4) * 16;
#pragma unroll
            for (int j = 0; j < 4; ++j) {
                unsigned int pk[4] = {0u, 0u, 0u, 0u};
                if (inb) {
#pragma unroll
                    for (int c4 = 0; c4 < 4; ++c4) {
                        unsigned int bb = 0u;
#pragma unroll
                        for (int cc = 0; cc < 4; ++cc) {
                            float q = rintf(v[c4 * 4 + cc][j] / 0.05f);
                            q = fminf(fmaxf(q, -128.0f), 127.0f);
                            bb |= ((unsigned int)(int)q & 0xffu) << (cc * 8);
                        }
                        pk[c4] = bb;
                    }
                }
                *(uint4*)(dst + j * 16) = make_uint4(pk[0], pk[1], pk[2], pk[3]);
            }
        } else {
            const int u    = t - 320;
            const int pc   = (u & 1) ? 65 : 0;
            const int half = (u >> 1) & 1;
            const int row  = u >> 2;
            const int h    = h0 + row;
            const int w    = bx * TW - 1 + pc;
            const bool inb = (unsigned)h < (unsigned)HD && (unsigned)w < (unsigned)WD;
            float v[16];
            if (inb) {
                const float* xp = x + ((size_t)(n * CIN + half * 16) * HD + h) * WD + w;
#pragma unroll
                for (int c = 0; c < 16; ++c)
                    v[c] = xp[(size_t)c * (HD * WD)];
            }
            __builtin_amdgcn_sched_barrier(0);
            unsigned int pk[4] = {0u, 0u, 0u, 0u};
            if (inb) {
#pragma unroll
                for (int c4 = 0; c4 < 4; ++c4) {
                    unsigned int bb = 0u;
#pragma unroll
                    for (int cc = 0; cc < 4; ++cc) {
                        float q = rintf(v[c4 * 4 + cc] / 0.05f);
                        q = fminf(fmaxf(q, -128.0f), 127.0f);
                        bb |= ((unsigned int)(int)q & 0xffu) << (cc * 8);
                    }
                    pk[c4] = bb;
                }
            }
            *(uint4*)(xs + half * PLANE + ((size_t)row * XCOLS + pc) * 16) =
                make_uint4(pk[0], pk[1], pk[2], pk[3]);
        }
    }

    __syncthreads();

    const int lane = tid & 63;
    const int wave = tid >> 6;
    const int l15  = lane & 15;
    const int quad = lane >> 4;

    intx4 Af[3][2][2];
#pragma unroll
    for (int kh = 0; kh < 3; ++kh)
#pragma unroll
        for (int p = 0; p < 2; ++p)
#pragma unroll
            for (int hf = 0; hf < 2; ++hf)
                Af[kh][p][hf] = *(const intx4*)(wp + (((kh * 2 + p) * 32 + hf * 16 + l15) << 6) + quad * 16);

    int bi0[4], bi1[4];
#pragma unroll
    for (int r = 0; r < 4; ++r) { bi0[r] = bias[quad * 4 + r]; bi1[r] = bias[16 + quad * 4 + r]; }

    const int wseg = wave * 16;
    const unsigned char* bbase = xs + (size_t)(quad & 1) * PLANE
                               + ((size_t)(wseg + l15 + (quad >> 1))) * 16;

#pragma unroll
    for (int it = 0; it < 4; ++it) {
        intx4 Bw[4][2];
#pragma unroll
        for (int r = 0; r < 4; ++r)
#pragma unroll
            for (int p = 0; p < 2; ++p)
                Bw[r][p] = *(const intx4*)(bbase + (size_t)((2 * it + r) * XCOLS + 2 * p) * 16);

        intx4 acc[2][2];
#pragma unroll
        for (int o = 0; o < 2; ++o)
#pragma unroll
            for (int hf = 0; hf < 2; ++hf)
                acc[o][hf] = (intx4){0, 0, 0, 0};

#pragma unroll
        for (int o = 0; o < 2; ++o)
#pragma unroll
            for (int kh = 0; kh < 3; ++kh)
#pragma unroll
                for (int p = 0; p < 2; ++p) {
                    const intx4 b = Bw[o + kh][p];
                    acc[o][0] = __builtin_amdgcn_mfma_i32_16x16x64_i8(Af[kh][p][0], b, acc[o][0], 0, 0, 0);
                    acc[o][1] = __builtin_amdgcn_mfma_i32_16x16x64_i8(Af[kh][p][1], b, acc[o][1], 0, 0, 0);
                }

#pragma unroll
        for (int o = 0; o < 2; ++o) {
            const int h = by * TH + 2 * it + o;
            float* op0 = out + (((size_t)n * COUT + quad * 4) * HD + h) * WD + bx * TW + wseg + l15;
            float* op1 = op0 + (size_t)16 * HD * WD;
#pragma unroll
            for (int r = 0; r < 4; ++r) {
                int v0 = acc[o][0][r] + bi0[r];
                float yq0 = rintf((float)v0 * 0.01f);
                yq0 = fminf(fmaxf(yq0, -127.f), 127.f);
                op0[(size_t)r * (HD * WD)] = fmaxf(yq0 * 0.1f, 0.f);
                int v1 = acc[o][1][r] + bi1[r];
                float yq1 = rintf((float)v1 * 0.01f);
                yq1 = fminf(fmaxf(yq1, -127.f), 127.f);
                op1[(size_t)r * (HD * WD)] = fmaxf(yq1 * 0.1f, 0.f);
            }
        }
    }
}

extern "C" void kernel_launch(void* const* d_in, const int* in_sizes, int n_in,
                              void* d_out, int out_size, void* d_ws, size_t ws_size,
                              hipStream_t stream) {
    const float* x  = (const float*)d_in[0];
    const int*   wq = (const int*)d_in[1];
    const int*   bi = (const int*)d_in[2];
    float* out = (float*)d_out;

    if (ws_size >= WP_BYTES) {
        wpack_kernel<<<12, 256, 0, stream>>>(wq, (unsigned int*)d_ws);
        conv8_hi<<<dim3(WD / TW, HD / TH, N_IMG), dim3(256), 0, stream>>>(
            x, (const char*)d_ws, bi, out);
    } else {
        conv8_fused_lds<<<dim3(WD / TW, HD / TH, N_IMG), dim3(256), 0, stream>>>(x, wq, bi, out);
    }
}

// Round 7
// 625.277 us; speedup vs baseline: 1.5142x; 1.5142x over previous
//
#include <hip/hip_runtime.h>

// Conv2dInt8 R10: R9 structure with the register cap relaxed.
// R9 post-mortem: __launch_bounds__(256,7) (cap 73 VGPR) forced a spill collapse
// (VGPR 60->36, scratch round-trip: FETCH 1.01GB / WRITE 1.19GB, 649us). The
// occupancy mechanism itself worked (72%, 3.47 TB/s). Fix: cap 102 via
// __launch_bounds__(256,5) — above the kernel's ~80-VGPR natural peak, so no
// spill; occupancy stays LDS/actual-VGPR-bound at 6-7 blocks/CU (LDS 22KB -> 7).
// Everything else byte-identical to R9 (passed, absmax 0.25).

#define N_IMG 8
#define CIN   32
#define COUT  32
#define HD    512
#define WD    512
#define TH    8
#define TW    64
#define XROWS 10
#define XCOLS 68
#define PLANE (XROWS * XCOLS * 16)   // 10880 B per 16-channel plane
#define WP_BYTES (6 * 32 * 64)       // 12288

typedef int intx4 __attribute__((ext_vector_type(4)));
typedef float floatx4 __attribute__((ext_vector_type(4)));

// ---------------- dispatch 1: pack weights int32 OIHW -> int8 wp in d_ws ----------------
// wp[(kh*2+pair)*32+cout][sel*32+cin], kw = pair*2+sel; kw==3 slots zero. (R5/R7 formula.)
__global__ __launch_bounds__(256) void wpack_kernel(const int* __restrict__ wq,
                                                    unsigned int* __restrict__ wp) {
    const int d    = blockIdx.x * 256 + threadIdx.x;   // dword id, 3072 total
    const int row  = d >> 4;
    const int k0   = (d & 15) * 4;
    const int khp  = row >> 5;
    const int cout = row & 31;
    const int kh   = khp >> 1;
    const int pr   = khp & 1;
    const int sel  = k0 >> 5;
    const int kw   = pr * 2 + sel;
    unsigned int pk = 0u;
    if (kw < 3) {
        const int cin0 = k0 & 31;
        const int* wqp = wq + ((cout * CIN + cin0) * 3 + kh) * 3 + kw;  // OIHW, cin stride 9
        unsigned int b0 = (unsigned int)(wqp[0]  - 128) & 0xffu;
        unsigned int b1 = (unsigned int)(wqp[9]  - 128) & 0xffu;
        unsigned int b2 = (unsigned int)(wqp[18] - 128) & 0xffu;
        unsigned int b3 = (unsigned int)(wqp[27] - 128) & 0xffu;
        pk = b0 | (b1 << 8) | (b2 << 16) | (b3 << 24);
    }
    wp[d] = pk;
}

// ---------------- dispatch 2: fused quant + conv, high occupancy, no spill ----------------
__global__ __launch_bounds__(256, 5) void conv8_hi(const float* __restrict__ x,
                                                   const char* __restrict__ wp,
                                                   const int* __restrict__ bias,
                                                   float* __restrict__ out)
{
    __shared__ alignas(16) unsigned char xs[2 * PLANE];   // 21760 B (only LDS)

    const int tid = threadIdx.x;
    const int bx = blockIdx.x;   // w tile (64 px)
    const int by = blockIdx.y;   // h tile (8 rows)
    const int n  = blockIdx.z;

    // ---- stage input: fp32 NCHW -> int8 [half][pix][16] LDS planes (R7 verbatim) ----
    const int h0 = by * TH - 1;
    for (int t = tid; t < 360; t += 256) {
        if (t < 320) {
            const int g    = t & 15;
            const int half = (t >> 4) & 1;
            const int row  = t >> 5;
            const int h    = h0 + row;
            const bool inb = (unsigned)h < (unsigned)HD;
            floatx4 v[16];
            if (inb) {
                const float* xp = x + ((size_t)(n * CIN + half * 16) * HD + h) * WD + bx * TW + g * 4;
#pragma unroll
                for (int c = 0; c < 16; ++c)
                    v[c] = *(const floatx4*)(xp + (size_t)c * (HD * WD));
            }
            __builtin_amdgcn_sched_barrier(0);   // keep the load batch issued together
            unsigned char* dst = xs + half * PLANE + ((size_t)row * XCOLS + 1 + g * 4) * 16;
#pragma unroll
            for (int j = 0; j < 4; ++j) {        // pixel within the float4
                unsigned int pk[4] = {0u, 0u, 0u, 0u};
                if (inb) {
#pragma unroll
                    for (int c4 = 0; c4 < 4; ++c4) {
                        unsigned int bb = 0u;
#pragma unroll
                        for (int cc = 0; cc < 4; ++cc) {
                            float q = rintf(v[c4 * 4 + cc][j] / 0.05f);   // identical numerics
                            q = fminf(fmaxf(q, -128.0f), 127.0f);
                            bb |= ((unsigned int)(int)q & 0xffu) << (cc * 8);
                        }
                        pk[c4] = bb;
                    }
                }
                *(uint4*)(dst + j * 16) = make_uint4(pk[0], pk[1], pk[2], pk[3]);
            }
        } else {
            const int u    = t - 320;            // 0..39: halo cols pc in {0,65}
            const int pc   = (u & 1) ? 65 : 0;
            const int half = (u >> 1) & 1;
            const int row  = u >> 2;
            const int h    = h0 + row;
            const int w    = bx * TW - 1 + pc;
            const bool inb = (unsigned)h < (unsigned)HD && (unsigned)w < (unsigned)WD;
            float v[16];
            if (inb) {
                const float* xp = x + ((size_t)(n * CIN + half * 16) * HD + h) * WD + w;
#pragma unroll
                for (int c = 0; c < 16; ++c)
                    v[c] = xp[(size_t)c * (HD * WD)];
            }
            __builtin_amdgcn_sched_barrier(0);
            unsigned int pk[4] = {0u, 0u, 0u, 0u};
            if (inb) {
#pragma unroll
                for (int c4 = 0; c4 < 4; ++c4) {
                    unsigned int bb = 0u;
#pragma unroll
                    for (int cc = 0; cc < 4; ++cc) {
                        float q = rintf(v[c4 * 4 + cc] / 0.05f);
                        q = fminf(fmaxf(q, -128.0f), 127.0f);
                        bb |= ((unsigned int)(int)q & 0xffu) << (cc * 8);
                    }
                    pk[c4] = bb;
                }
            }
            *(uint4*)(xs + half * PLANE + ((size_t)row * XCOLS + pc) * 16) =
                make_uint4(pk[0], pk[1], pk[2], pk[3]);
        }
    }

    __syncthreads();

    // ---- compute: R7 MFMA plan; A-frags read from GLOBAL wp (L2-resident) ----
    const int lane = tid & 63;
    const int wave = tid >> 6;
    const int l15  = lane & 15;
    const int quad = lane >> 4;

    intx4 Af[3][2][2];
#pragma unroll
    for (int kh = 0; kh < 3; ++kh)
#pragma unroll
        for (int p = 0; p < 2; ++p)
#pragma unroll
            for (int hf = 0; hf < 2; ++hf)
                Af[kh][p][hf] = *(const intx4*)(wp + (((kh * 2 + p) * 32 + hf * 16 + l15) << 6) + quad * 16);

    int bi0[4], bi1[4];
#pragma unroll
    for (int r = 0; r < 4; ++r) { bi0[r] = bias[quad * 4 + r]; bi1[r] = bias[16 + quad * 4 + r]; }

    const int wseg = wave * 16;
    // k = quad*16 + j -> kw-sel = quad>>1 (pixel offset), ch-half = quad&1 (plane), cin = (quad&1)*16 + j
    const unsigned char* bbase = xs + (size_t)(quad & 1) * PLANE
                               + ((size_t)(wseg + l15 + (quad >> 1))) * 16;

#pragma unroll
    for (int it = 0; it < 4; ++it) {
        intx4 Bw[4][2];
#pragma unroll
        for (int r = 0; r < 4; ++r)
#pragma unroll
            for (int p = 0; p < 2; ++p)
                Bw[r][p] = *(const intx4*)(bbase + (size_t)((2 * it + r) * XCOLS + 2 * p) * 16);

        intx4 acc[2][2];
#pragma unroll
        for (int o = 0; o < 2; ++o)
#pragma unroll
            for (int hf = 0; hf < 2; ++hf)
                acc[o][hf] = (intx4){0, 0, 0, 0};

#pragma unroll
        for (int o = 0; o < 2; ++o)
#pragma unroll
            for (int kh = 0; kh < 3; ++kh)
#pragma unroll
                for (int p = 0; p < 2; ++p) {
                    const intx4 b = Bw[o + kh][p];
                    acc[o][0] = __builtin_amdgcn_mfma_i32_16x16x64_i8(Af[kh][p][0], b, acc[o][0], 0, 0, 0);
                    acc[o][1] = __builtin_amdgcn_mfma_i32_16x16x64_i8(Af[kh][p][1], b, acc[o][1], 0, 0, 0);
                }

#pragma unroll
        for (int o = 0; o < 2; ++o) {
            const int h = by * TH + 2 * it + o;
            float* op0 = out + (((size_t)n * COUT + quad * 4) * HD + h) * WD + bx * TW + wseg + l15;
            float* op1 = op0 + (size_t)16 * HD * WD;
#pragma unroll
            for (int r = 0; r < 4; ++r) {
                int v0 = acc[o][0][r] + bi0[r];
                float yq0 = rintf((float)v0 * 0.01f);
                yq0 = fminf(fmaxf(yq0, -127.f), 127.f);
                op0[(size_t)r * (HD * WD)] = fmaxf(yq0 * 0.1f, 0.f);
                int v1 = acc[o][1][r] + bi1[r];
                float yq1 = rintf((float)v1 * 0.01f);
                yq1 = fminf(fmaxf(yq1, -127.f), 127.f);
                op1[(size_t)r * (HD * WD)] = fmaxf(yq1 * 0.1f, 0.f);
            }
        }
    }
}

// ---------------- fallback: R7 self-contained kernel (weights staged in LDS) ----------------
__global__ __launch_bounds__(256, 4) void conv8_fused_lds(const float* __restrict__ x,
                                                          const int* __restrict__ wq,
                                                          const int* __restrict__ bias,
                                                          float* __restrict__ out)
{
    __shared__ alignas(16) unsigned char xs[2 * PLANE];
    __shared__ alignas(16) char wp[6 * 32 * 64];

    const int tid = threadIdx.x;
    const int bx = blockIdx.x, by = blockIdx.y, n = blockIdx.z;

#pragma unroll
    for (int k = 0; k < 12; ++k) {
        const int d    = tid + k * 256;
        const int row  = d >> 4;
        const int k0   = (d & 15) * 4;
        const int khp  = row >> 5;
        const int cout = row & 31;
        const int kh   = khp >> 1;
        const int pr   = khp & 1;
        const int sel  = k0 >> 5;
        const int kw   = pr * 2 + sel;
        unsigned int pk = 0u;
        if (kw < 3) {
            const int cin0 = k0 & 31;
            const int* wqp = wq + ((cout * CIN + cin0) * 3 + kh) * 3 + kw;
            unsigned int b0 = (unsigned int)(wqp[0]  - 128) & 0xffu;
            unsigned int b1 = (unsigned int)(wqp[9]  - 128) & 0xffu;
            unsigned int b2 = (unsigned int)(wqp[18] - 128) & 0xffu;
            unsigned int b3 = (unsigned int)(wqp[27] - 128) & 0xffu;
            pk = b0 | (b1 << 8) | (b2 << 16) | (b3 << 24);
        }
        *(unsigned int*)(wp + d * 4) = pk;
    }

    const int h0 = by * TH - 1;
    for (int t = tid; t < 360; t += 256) {
        if (t < 320) {
            const int g    = t & 15;
            const int half = (t >> 4) & 1;
            const int row  = t >> 5;
            const int h    = h0 + row;
            const bool inb = (unsigned)h < (unsigned)HD;
            floatx4 v[16];
            if (inb) {
                const float* xp = x + ((size_t)(n * CIN + half * 16) * HD + h) * WD + bx * TW + g * 4;
#pragma unroll
                for (int c = 0; c < 16; ++c)
                    v[c] = *(const floatx4*)(xp + (size_t)c * (HD * WD));
            }
            __builtin_amdgcn_sched_barrier(0);
            unsigned char* dst = xs + half * PLANE + ((size_t)row * XCOLS + 1 + g * 4) * 16;
#pragma unroll
            for (int j = 0; j < 4; ++j) {
                unsigned int pk[4] = {0u, 0u, 0u, 0u};
                if (inb) {
#pragma unroll
                    for (int c4 = 0; c4 < 4; ++c4) {
                        unsigned int bb = 0u;
#pragma unroll
                        for (int cc = 0; cc < 4; ++cc) {
                            float q = rintf(v[c4 * 4 + cc][j] / 0.05f);
                            q = fminf(fmaxf(q, -128.0f), 127.0f);
                            bb |= ((unsigned int)(int)q & 0xffu) << (cc * 8);
                        }
                        pk[c4] = bb;
                    }
                }
                *(uint4*)(dst + j * 16) = make_uint4(pk[0], pk[1], pk[2], pk[3]);
            }
        } else {
            const int u    = t - 320;
            const int pc   = (u & 1) ? 65 : 0;
            const int half = (u >> 1) & 1;
            const int row  = u >> 2;
            const int h    = h0 + row;
            const int w    = bx * TW - 1 + pc;
            const bool inb = (unsigned)h < (unsigned)HD && (unsigned)w < (unsigned)WD;
            float v[16];
            if (inb) {
                const float* xp = x + ((size_t)(n * CIN + half * 16) * HD + h) * WD + w;
#pragma unroll
                for (int c = 0; c < 16; ++c)
                    v[c] = xp[(size_t)c * (HD * WD)];
            }
            __builtin_amdgcn_sched_barrier(0);
            unsigned int pk[4] = {0u, 0u, 0u, 0u};
            if (inb) {
#pragma unroll
                for (int c4 = 0; c4 < 4; ++c4) {
                    unsigned int bb = 0u;
#pragma unroll
                    for (int cc = 0; cc < 4; ++cc) {
                        float q = rintf(v[c4 * 4 + cc] / 0.05f);
                        q = fminf(fmaxf(q, -128.0f), 127.0f);
                        bb |= ((unsigned int)(int)q & 0xffu) << (cc * 8);
                    }
                    pk[c4] = bb;
                }
            }
            *(uint4*)(xs + half * PLANE + ((size_t)row * XCOLS + pc) * 16) =
                make_uint4(pk[0], pk[1], pk[2], pk[3]);
        }
    }

    __syncthreads();

    const int lane = tid & 63;
    const int wave = tid >> 6;
    const int l15  = lane & 15;
    const int quad = lane >> 4;

    intx4 Af[3][2][2];
#pragma unroll
    for (int kh = 0; kh < 3; ++kh)
#pragma unroll
        for (int p = 0; p < 2; ++p)
#pragma unroll
            for (int hf = 0; hf < 2; ++hf)
                Af[kh][p][hf] = *(const intx4*)(wp + (((kh * 2 + p) * 32 + hf * 16 + l15) << 6) + quad * 16);

    int bi0[4], bi1[4];
#pragma unroll
    for (int r = 0; r < 4; ++r) { bi0[r] = bias[quad * 4 + r]; bi1[r] = bias[16 + quad * 4 + r]; }

    const int wseg = wave * 16;
    const unsigned char* bbase = xs + (size_t)(quad & 1) * PLANE
                               + ((size_t)(wseg + l15 + (quad >> 1))) * 16;

#pragma unroll
    for (int it = 0; it < 4; ++it) {
        intx4 Bw[4][2];
#pragma unroll
        for (int r = 0; r < 4; ++r)
#pragma unroll
            for (int p = 0; p < 2; ++p)
                Bw[r][p] = *(const intx4*)(bbase + (size_t)((2 * it + r) * XCOLS + 2 * p) * 16);

        intx4 acc[2][2];
#pragma unroll
        for (int o = 0; o < 2; ++o)
#pragma unroll
            for (int hf = 0; hf < 2; ++hf)
                acc[o][hf] = (intx4){0, 0, 0, 0};

#pragma unroll
        for (int o = 0; o < 2; ++o)
#pragma unroll
            for (int kh = 0; kh < 3; ++kh)
#pragma unroll
                for (int p = 0; p < 2; ++p) {
                    const intx4 b = Bw[o + kh][p];
                    acc[o][0] = __builtin_amdgcn_mfma_i32_16x16x64_i8(Af[kh][p][0], b, acc[o][0], 0, 0, 0);
                    acc[o][1] = __builtin_amdgcn_mfma_i32_16x16x64_i8(Af[kh][p][1], b, acc[o][1], 0, 0, 0);
                }

#pragma unroll
        for (int o = 0; o < 2; ++o) {
            const int h = by * TH + 2 * it + o;
            float* op0 = out + (((size_t)n * COUT + quad * 4) * HD + h) * WD + bx * TW + wseg + l15;
            float* op1 = op0 + (size_t)16 * HD * WD;
#pragma unroll
            for (int r = 0; r < 4; ++r) {
                int v0 = acc[o][0][r] + bi0[r];
                float yq0 = rintf((float)v0 * 0.01f);
                yq0 = fminf(fmaxf(yq0, -127.f), 127.f);
                op0[(size_t)r * (HD * WD)] = fmaxf(yq0 * 0.1f, 0.f);
                int v1 = acc[o][1][r] + bi1[r];
                float yq1 = rintf((float)v1 * 0.01f);
                yq1 = fminf(fmaxf(yq1, -127.f), 127.f);
                op1[(size_t)r * (HD * WD)] = fmaxf(yq1 * 0.1f, 0.f);
            }
        }
    }
}

extern "C" void kernel_launch(void* const* d_in, const int* in_sizes, int n_in,
                              void* d_out, int out_size, void* d_ws, size_t ws_size,
                              hipStream_t stream) {
    const float* x  = (const float*)d_in[0];
    const int*   wq = (const int*)d_in[1];
    const int*   bi = (const int*)d_in[2];
    float* out = (float*)d_out;

    if (ws_size >= WP_BYTES) {
        wpack_kernel<<<12, 256, 0, stream>>>(wq, (unsigned int*)d_ws);
        conv8_hi<<<dim3(WD / TW, HD / TH, N_IMG), dim3(256), 0, stream>>>(
            x, (const char*)d_ws, bi, out);
    } else {
        conv8_fused_lds<<<dim3(WD / TW, HD / TH, N_IMG), dim3(256), 0, stream>>>(x, wq, bi, out);
    }
}